// Round 1
// baseline (19766.360 us; speedup 1.0000x reference)
//
#include <hip/hip_runtime.h>
#include <cstdint>
#include <cmath>

// ---------------------------------------------------------------------------
// SelectiveWhElmanCell — round 0, correctness-first fp32 implementation.
//
// Phases:
//  1) threefry RNG (key 42, partitionable counters) -> u0; 3-step power
//     iteration on W_h -> scale = 0.99/(sigma+eps) in ws.
//  2) fused dual GEMM: xw = x@W_x^T + b  -> stored at out[t] slots
//                      gate = sigmoid(x@W_gate^T) -> stored at h[t+1] slots
//  3) 256 sequential step kernels: Rh = h_prev@W_h^T*scale,
//     h = tanh(xw + Rh*gate), out = h*silu(z). In-place overwrite of the
//     scratch slots (each thread reads its element before writing it).
// ---------------------------------------------------------------------------

#define THREEFRY_PARTITIONABLE 1

static constexpr int Tt = 256;
static constexpr int Bb = 64;
static constexpr int Dk = 2048;
static constexpr int Mrows = Tt * Bb;          // 16384
static constexpr float EPSF = 1e-8f;
static constexpr float TARGET_RADIUS = 0.99f;

// ------------------------------ threefry -----------------------------------
__device__ __forceinline__ void tf_round(uint32_t& x0, uint32_t& x1, int r) {
    x0 += x1;
    x1 = (x1 << r) | (x1 >> (32 - r));
    x1 ^= x0;
}

__device__ __forceinline__ uint2 threefry2x32(uint32_t ks0, uint32_t ks1,
                                              uint32_t x0, uint32_t x1) {
    uint32_t ks2 = ks0 ^ ks1 ^ 0x1BD11BDAu;
    x0 += ks0; x1 += ks1;
    tf_round(x0,x1,13); tf_round(x0,x1,15); tf_round(x0,x1,26); tf_round(x0,x1,6);
    x0 += ks1; x1 += ks2 + 1u;
    tf_round(x0,x1,17); tf_round(x0,x1,29); tf_round(x0,x1,16); tf_round(x0,x1,24);
    x0 += ks2; x1 += ks0 + 2u;
    tf_round(x0,x1,13); tf_round(x0,x1,15); tf_round(x0,x1,26); tf_round(x0,x1,6);
    x0 += ks0; x1 += ks1 + 3u;
    tf_round(x0,x1,17); tf_round(x0,x1,29); tf_round(x0,x1,16); tf_round(x0,x1,24);
    x0 += ks1; x1 += ks2 + 4u;
    tf_round(x0,x1,13); tf_round(x0,x1,15); tf_round(x0,x1,26); tf_round(x0,x1,6);
    x0 += ks2; x1 += ks0 + 5u;
    return make_uint2(x0, x1);
}

// u0 = normal(key(42), (2048,)); u0 /= ||u0||  (no eps on first normalize).
__global__ __launch_bounds__(256) void k_rng(float* __restrict__ u) {
    __shared__ float red[256];
    __shared__ float s_inv;
    float local = 0.f;
    for (int i = threadIdx.x; i < Dk; i += 256) {
        uint32_t bits;
#if THREEFRY_PARTITIONABLE
        uint2 r = threefry2x32(0u, 42u, 0u, (uint32_t)i);
        bits = r.x ^ r.y;
#else
        if (i < Dk / 2) {
            uint2 r = threefry2x32(0u, 42u, (uint32_t)i, (uint32_t)(i + Dk / 2));
            bits = r.x;
        } else {
            uint2 r = threefry2x32(0u, 42u, (uint32_t)(i - Dk / 2), (uint32_t)i);
            bits = r.y;
        }
#endif
        uint32_t fb = (bits >> 9) | 0x3f800000u;
        float f01 = __uint_as_float(fb) - 1.0f;           // [0,1)
        const float lo = -0.99999994f;                    // nextafter(-1,0)
        float uu = f01 * (1.0f - lo) + lo;                // (1-lo) folds to 2.0f
        uu = fmaxf(lo, uu);
        float g = 1.41421356237f * erfinvf(uu);
        u[i] = g;
        local += g * g;
    }
    red[threadIdx.x] = local;
    __syncthreads();
    for (int s = 128; s > 0; s >>= 1) {
        if (threadIdx.x < s) red[threadIdx.x] += red[threadIdx.x + s];
        __syncthreads();
    }
    if (threadIdx.x == 0) s_inv = 1.0f / sqrtf(red[0]);
    __syncthreads();
    float inv = s_inv;
    for (int i = threadIdx.x; i < Dk; i += 256) u[i] *= inv;
}

// out[j] = sum_i W[i,j] * u[i]   (W^T @ u)
__global__ __launch_bounds__(256) void k_matvec_T(const float* __restrict__ W,
                                                  const float* __restrict__ u,
                                                  float* __restrict__ out) {
    __shared__ float us[Dk];
    for (int i = threadIdx.x; i < Dk; i += 256) us[i] = u[i];
    __syncthreads();
    int j = blockIdx.x * 256 + threadIdx.x;
    float acc = 0.f;
    for (int i = 0; i < Dk; ++i) acc += W[(size_t)i * Dk + j] * us[i];
    out[j] = acc;
}

// out[row] = sum_j W[row,j] * v[j]   (W @ v), one block per row
__global__ __launch_bounds__(256) void k_matvec_N(const float* __restrict__ W,
                                                  const float* __restrict__ v,
                                                  float* __restrict__ out) {
    __shared__ float red[256];
    const float* Wr = W + (size_t)blockIdx.x * Dk;
    float acc = 0.f;
    for (int j = threadIdx.x; j < Dk; j += 256) acc += Wr[j] * v[j];
    red[threadIdx.x] = acc;
    __syncthreads();
    for (int s = 128; s > 0; s >>= 1) {
        if (threadIdx.x < s) red[threadIdx.x] += red[threadIdx.x + s];
        __syncthreads();
    }
    if (threadIdx.x == 0) out[blockIdx.x] = red[0];
}

// vec /= (||vec|| + eps)
__global__ __launch_bounds__(256) void k_normalize(float* __restrict__ vec) {
    __shared__ float red[256];
    __shared__ float s_inv;
    float acc = 0.f;
    for (int i = threadIdx.x; i < Dk; i += 256) { float x = vec[i]; acc += x * x; }
    red[threadIdx.x] = acc;
    __syncthreads();
    for (int s = 128; s > 0; s >>= 1) {
        if (threadIdx.x < s) red[threadIdx.x] += red[threadIdx.x + s];
        __syncthreads();
    }
    if (threadIdx.x == 0) s_inv = 1.0f / (sqrtf(red[0]) + EPSF);
    __syncthreads();
    float inv = s_inv;
    for (int i = threadIdx.x; i < Dk; i += 256) vec[i] *= inv;
}

// sigma = ||uraw||^2/(||uraw||+eps); scale = 0.99/(sigma+eps)
__global__ __launch_bounds__(256) void k_sigma(const float* __restrict__ uraw,
                                               float* __restrict__ scale_out) {
    __shared__ float red[256];
    float acc = 0.f;
    for (int i = threadIdx.x; i < Dk; i += 256) { float x = uraw[i]; acc += x * x; }
    red[threadIdx.x] = acc;
    __syncthreads();
    for (int s = 128; s > 0; s >>= 1) {
        if (threadIdx.x < s) red[threadIdx.x] += red[threadIdx.x + s];
        __syncthreads();
    }
    if (threadIdx.x == 0) {
        float ss = red[0];
        float n = sqrtf(ss);
        float sigma = ss / (n + EPSF);
        scale_out[0] = TARGET_RADIUS / (sigma + EPSF);
    }
}

// --------------------------- fused dual GEMM -------------------------------
// xw[m,n]   = sum_k X[m,k]*Wx[n,k] + bias[n]
// gate[m,n] = sigmoid(sum_k X[m,k]*Wg[n,k])
// BM=BN=64, BK=16, 256 threads, 4x4 micro-tile per thread.
__global__ __launch_bounds__(256) void k_dualgemm(const float* __restrict__ X,
                                                  const float* __restrict__ Wx,
                                                  const float* __restrict__ Wg,
                                                  const float* __restrict__ bias,
                                                  float* __restrict__ xw_out,
                                                  float* __restrict__ gate_out) {
    __shared__ float As[16][68];   // [k][m], +4 pad keeps float4 alignment
    __shared__ float Bxs[16][68];  // [k][n]
    __shared__ float Bgs[16][68];

    const int tid = threadIdx.x;
    const int bm = blockIdx.x;   // 0..255
    const int bn = blockIdx.y;   // 0..31
    const int tx = tid & 15;     // n-group
    const int ty = tid >> 4;     // m-group

    float accX[4][4] = {};
    float accG[4][4] = {};

    const int lrow = tid >> 2;        // 0..63
    const int lk4  = (tid & 3) * 4;   // 0,4,8,12
    const float* Xp  = X  + (size_t)(bm * 64 + lrow) * Dk + lk4;
    const float* Wxp = Wx + (size_t)(bn * 64 + lrow) * Dk + lk4;
    const float* Wgp = Wg + (size_t)(bn * 64 + lrow) * Dk + lk4;

    for (int k0 = 0; k0 < Dk; k0 += 16) {
        float4 xa  = *(const float4*)(Xp  + k0);
        float4 wxa = *(const float4*)(Wxp + k0);
        float4 wga = *(const float4*)(Wgp + k0);
        __syncthreads();
        As [lk4 + 0][lrow] = xa.x;  As [lk4 + 1][lrow] = xa.y;
        As [lk4 + 2][lrow] = xa.z;  As [lk4 + 3][lrow] = xa.w;
        Bxs[lk4 + 0][lrow] = wxa.x; Bxs[lk4 + 1][lrow] = wxa.y;
        Bxs[lk4 + 2][lrow] = wxa.z; Bxs[lk4 + 3][lrow] = wxa.w;
        Bgs[lk4 + 0][lrow] = wga.x; Bgs[lk4 + 1][lrow] = wga.y;
        Bgs[lk4 + 2][lrow] = wga.z; Bgs[lk4 + 3][lrow] = wga.w;
        __syncthreads();
#pragma unroll
        for (int kk = 0; kk < 16; ++kk) {
            const float4 a  = *(const float4*)&As [kk][ty * 4];
            const float4 bx = *(const float4*)&Bxs[kk][tx * 4];
            const float4 bg = *(const float4*)&Bgs[kk][tx * 4];
            float av[4]  = {a.x, a.y, a.z, a.w};
            float bxv[4] = {bx.x, bx.y, bx.z, bx.w};
            float bgv[4] = {bg.x, bg.y, bg.z, bg.w};
#pragma unroll
            for (int i = 0; i < 4; ++i)
#pragma unroll
                for (int j = 0; j < 4; ++j) {
                    accX[i][j] += av[i] * bxv[j];
                    accG[i][j] += av[i] * bgv[j];
                }
        }
    }

    const int m0 = bm * 64 + ty * 4;
    const int n0 = bn * 64 + tx * 4;
    float4 bv = *(const float4*)(bias + n0);
#pragma unroll
    for (int i = 0; i < 4; ++i) {
        float4 xo, go;
        xo.x = accX[i][0] + bv.x; xo.y = accX[i][1] + bv.y;
        xo.z = accX[i][2] + bv.z; xo.w = accX[i][3] + bv.w;
        go.x = 1.0f / (1.0f + expf(-accG[i][0]));
        go.y = 1.0f / (1.0f + expf(-accG[i][1]));
        go.z = 1.0f / (1.0f + expf(-accG[i][2]));
        go.w = 1.0f / (1.0f + expf(-accG[i][3]));
        *(float4*)(xw_out   + (size_t)(m0 + i) * Dk + n0) = xo;
        *(float4*)(gate_out + (size_t)(m0 + i) * Dk + n0) = go;
    }
}

// ------------------------------ step kernel --------------------------------
// Rh[b,e] = scale * sum_d h_prev[b,d]*Wh[e,d]
// h_new = tanh(xw + Rh*gate); out = h_new*silu(z)
// xw lives at out[t] (overwritten with out), gate lives at h[t+1]
// (overwritten with h_new). BM=32(b) x BN=32(e), BK=32, 2x2 micro.
__global__ __launch_bounds__(256) void k_step(const float* __restrict__ Wh,
                                              const float* __restrict__ scale_p,
                                              const float* __restrict__ z_t,
                                              float* __restrict__ xw_t,
                                              const float* __restrict__ h_prev,
                                              float* __restrict__ hg_t) {
    __shared__ float Hs[32][36];  // [k][b]
    __shared__ float Ws[32][36];  // [k][e]
    const int tid = threadIdx.x;
    const int bn = blockIdx.x;  // 0..63 (e tiles)
    const int bb = blockIdx.y;  // 0..1  (b tiles)
    const int tx = tid & 15;    // e group
    const int ty = tid >> 4;    // b group

    float a00 = 0.f, a01 = 0.f, a10 = 0.f, a11 = 0.f;

    const int lrow = tid >> 3;        // 0..31
    const int lk4  = (tid & 7) * 4;   // 0..28
    const float* Hp = h_prev + (size_t)(bb * 32 + lrow) * Dk + lk4;
    const float* Wp = Wh     + (size_t)(bn * 32 + lrow) * Dk + lk4;

    for (int k0 = 0; k0 < Dk; k0 += 32) {
        float4 ha = *(const float4*)(Hp + k0);
        float4 wa = *(const float4*)(Wp + k0);
        __syncthreads();
        Hs[lk4 + 0][lrow] = ha.x; Hs[lk4 + 1][lrow] = ha.y;
        Hs[lk4 + 2][lrow] = ha.z; Hs[lk4 + 3][lrow] = ha.w;
        Ws[lk4 + 0][lrow] = wa.x; Ws[lk4 + 1][lrow] = wa.y;
        Ws[lk4 + 2][lrow] = wa.z; Ws[lk4 + 3][lrow] = wa.w;
        __syncthreads();
#pragma unroll
        for (int kk = 0; kk < 32; ++kk) {
            float2 hv = *(const float2*)&Hs[kk][ty * 2];
            float2 wv = *(const float2*)&Ws[kk][tx * 2];
            a00 += hv.x * wv.x; a01 += hv.x * wv.y;
            a10 += hv.y * wv.x; a11 += hv.y * wv.y;
        }
    }

    const float sc = scale_p[0];
    const int e0 = bn * 32 + tx * 2;
    const int b0 = bb * 32 + ty * 2;
    float acc[2][2] = {{a00, a01}, {a10, a11}};
#pragma unroll
    for (int i = 0; i < 2; ++i)
#pragma unroll
        for (int j = 0; j < 2; ++j) {
            size_t idx = (size_t)(b0 + i) * Dk + (e0 + j);
            float Rh = acc[i][j] * sc;
            float g = hg_t[idx];
            float pre = xw_t[idx] + Rh * g;
            float hn = tanhf(pre);
            float zv = z_t[idx];
            float sz = zv / (1.0f + expf(-zv));
            hg_t[idx] = hn;          // h[t+1] overwrites gate slot
            xw_t[idx] = hn * sz;     // out[t] overwrites xw slot
        }
}

// ------------------------------- launch ------------------------------------
extern "C" void kernel_launch(void* const* d_in, const int* in_sizes, int n_in,
                              void* d_out, int out_size, void* d_ws, size_t ws_size,
                              hipStream_t stream) {
    const float* x    = (const float*)d_in[0];
    const float* z    = (const float*)d_in[1];
    const float* h0   = (const float*)d_in[2];
    const float* Wx   = (const float*)d_in[3];
    const float* Wh   = (const float*)d_in[4];
    const float* Wg   = (const float*)d_in[5];
    const float* bias = (const float*)d_in[6];

    float* out  = (float*)d_out;                      // [T,B,D]
    float* hbuf = out + (size_t)Tt * Bb * Dk;         // [T+1,B,D]

    float* ws    = (float*)d_ws;
    float* u     = ws;          // 2048
    float* v     = ws + 2048;   // 2048
    float* tmp   = ws + 4096;   // 2048
    float* scale = ws + 6144;   // 1

    const size_t BD = (size_t)Bb * Dk;

    // h[0] = h0
    hipMemcpyAsync(hbuf, h0, BD * sizeof(float), hipMemcpyDeviceToDevice, stream);

    // spectral norm scale
    k_rng<<<1, 256, 0, stream>>>(u);
    float* uc = u;
    float* ut = tmp;
    for (int it = 0; it < 3; ++it) {
        k_matvec_T<<<8, 256, 0, stream>>>(Wh, uc, v);
        k_normalize<<<1, 256, 0, stream>>>(v);
        k_matvec_N<<<2048, 256, 0, stream>>>(Wh, v, ut);
        if (it < 2) {
            k_normalize<<<1, 256, 0, stream>>>(ut);
            float* t2 = uc; uc = ut; ut = t2;
        }
    }
    k_sigma<<<1, 256, 0, stream>>>(ut, scale);

    // fused input projections: xw -> out[t] slots, gate -> h[t+1] slots
    dim3 gg(Mrows / 64, Dk / 64);
    k_dualgemm<<<gg, 256, 0, stream>>>(x, Wx, Wg, bias, out, hbuf + BD);

    // sequential recurrence
    dim3 gs(Dk / 32, Bb / 32);
    for (int t = 0; t < Tt; ++t) {
        k_step<<<gs, 256, 0, stream>>>(Wh, scale,
                                       z + (size_t)t * BD,
                                       out + (size_t)t * BD,
                                       hbuf + (size_t)t * BD,
                                       hbuf + (size_t)(t + 1) * BD);
    }
}